// Round 1
// baseline (407.937 us; speedup 1.0000x reference)
//
#include <hip/hip_runtime.h>
#include <cstddef>

// MixModel: out = outreg + outnet
//   outreg: per-element quadratic features dotted with reg1/reg2
//   outnet: h = tanh(u[even] @ W1 + b1); out0 = h@W2a+b2a (18x3); out1 = h@W2b+b2b (18x4)
//           combined with shifted u (uA,uB,uC)
// One thread per row. Weights are wave-uniform -> scalar loads (scalar pipe),
// 126 accumulators + 36 u values in VGPRs.

__device__ __forceinline__ float tanh_fast(float x) {
    // 1 - 2/(exp(2x)+1): monotone-safe at +/-inf (no NaN), ~1e-7 rel err
    const float e2 = __expf(2.0f * x);
    return 1.0f - __fdividef(2.0f, e2 + 1.0f);
}

__global__ __launch_bounds__(256, 2) void mixmodel_kernel(
    const float* __restrict__ u,      // N*36
    const float* __restrict__ reg1,   // 6
    const float* __restrict__ reg2,   // 4
    const float* __restrict__ W1,     // 18*128
    const float* __restrict__ b1,     // 128
    const float* __restrict__ W2a,    // 128*54
    const float* __restrict__ b2a,    // 54
    const float* __restrict__ W2b,    // 128*72
    const float* __restrict__ b2b,    // 72
    float* __restrict__ out,          // N*36
    int N)
{
    const int row = blockIdx.x * blockDim.x + threadIdx.x;
    if (row >= N) return;

    // ---- load full u row (144B, 16B-aligned) ----
    const float* ur = u + (size_t)row * 36;
    float uu[36];
#pragma unroll
    for (int q = 0; q < 9; ++q) {
        const float4 v = reinterpret_cast<const float4*>(ur)[q];
        uu[4*q+0] = v.x; uu[4*q+1] = v.y; uu[4*q+2] = v.z; uu[4*q+3] = v.w;
    }

    // ---- accumulators initialized with biases ----
    float acc0[54];
    float acc1[72];
#pragma unroll
    for (int e = 0; e < 54; ++e) acc0[e] = b2a[e];
#pragma unroll
    for (int e = 0; e < 72; ++e) acc1[e] = b2b[e];

    // ---- main loop over hidden units ----
#pragma unroll 2
    for (int j = 0; j < 128; ++j) {
        float x = b1[j];
#pragma unroll
        for (int k = 0; k < 18; ++k)
            x = fmaf(uu[2*k], W1[k*128 + j], x);   // W1[k][j], uniform -> s_load
        const float h = tanh_fast(x);
#pragma unroll
        for (int e = 0; e < 54; ++e)
            acc0[e] = fmaf(h, W2a[j*54 + e], acc0[e]);  // uniform row -> s_load
#pragma unroll
        for (int e = 0; e < 72; ++e)
            acc1[e] = fmaf(h, W2b[j*72 + e], acc1[e]);
    }

    // ---- epilogue: combine with shifted u + regression part ----
    const float r10 = reg1[0], r11 = reg1[1], r12 = reg1[2];
    const float r13 = reg1[3], r14 = reg1[4], r15 = reg1[5];
    const float r20 = reg2[0], r21 = reg2[1], r22 = reg2[2], r23 = reg2[3];

    float res[36];
#pragma unroll
    for (int i = 0; i < 18; ++i) {
        const int ie = 2*i, io = 2*i+1;
        const float uA  = uu[(ie + 35) % 36];  // u[(2i-1)%36]
        const float uB  = uu[io];              // u[2i+1]
        const float uC  = uu[(ie + 3) % 36];   // u[(2i+3)%36]
        const float um2 = uu[(ie + 34) % 36];  // u[(2i-2)%36]
        const float up2 = uu[(ie + 2) % 36];   // u[(2i+2)%36]
        const float ue  = uu[ie];

        // outnet even: out0[i,0] + out0[i,1]*uA + out0[i,2]*uB
        float oe = acc0[3*i];
        oe = fmaf(acc0[3*i+1], uA, oe);
        oe = fmaf(acc0[3*i+2], uB, oe);

        // outnet odd: out1[i,0] + out1[i,1]*uA + out1[i,2]*uB + out1[i,3]*uC
        float oo = acc1[4*i];
        oo = fmaf(acc1[4*i+1], uA, oo);
        oo = fmaf(acc1[4*i+2], uB, oo);
        oo = fmaf(acc1[4*i+3], uC, oo);

        // outreg even: reg1 . [ue, uB, um2*uA, uA*up2, ue*uB] + reg1[0]
        float re = r10;
        re = fmaf(r11, ue,      re);
        re = fmaf(r12, uB,      re);
        re = fmaf(r13, um2*uA,  re);
        re = fmaf(r14, uA*up2,  re);
        re = fmaf(r15, ue*uB,   re);

        // outreg odd: reg2 . [uB, uA*ue, ue*up2] + reg2[0]
        float ro = r20;
        ro = fmaf(r21, uB,     ro);
        ro = fmaf(r22, uA*ue,  ro);
        ro = fmaf(r23, ue*up2, ro);

        res[ie] = oe + re;
        res[io] = oo + ro;
    }

    // ---- store (144B, 16B-aligned) ----
    float4* op = reinterpret_cast<float4*>(out + (size_t)row * 36);
#pragma unroll
    for (int q = 0; q < 9; ++q)
        op[q] = make_float4(res[4*q], res[4*q+1], res[4*q+2], res[4*q+3]);
}

extern "C" void kernel_launch(void* const* d_in, const int* in_sizes, int n_in,
                              void* d_out, int out_size, void* d_ws, size_t ws_size,
                              hipStream_t stream) {
    // d_in order: t, u, reg1, reg2, W1, b1, W2a, b2a, W2b, b2b
    const float* u    = (const float*)d_in[1];
    const float* reg1 = (const float*)d_in[2];
    const float* reg2 = (const float*)d_in[3];
    const float* W1   = (const float*)d_in[4];
    const float* b1   = (const float*)d_in[5];
    const float* W2a  = (const float*)d_in[6];
    const float* b2a  = (const float*)d_in[7];
    const float* W2b  = (const float*)d_in[8];
    const float* b2b  = (const float*)d_in[9];
    float* out = (float*)d_out;

    const int N = in_sizes[1] / 36;
    const int block = 256;
    const int grid = (N + block - 1) / block;
    mixmodel_kernel<<<grid, block, 0, stream>>>(u, reg1, reg2, W1, b1,
                                                W2a, b2a, W2b, b2b, out, N);
}

// Round 2
// 274.010 us; speedup vs baseline: 1.4888x; 1.4888x over previous
//
#include <hip/hip_runtime.h>
#include <cstddef>

// MixModel via bf16 MFMA:
//   GEMM1: u_even[N x 18(pad32)] @ W1[18(pad32) x 128] -> tanh -> h
//   GEMM2: h[N x 128] @ W2comb[128 x 126(pad128)]      -> C2
//   epilogue: combine C2 (18x3 / 18x4 groups) with shifted u + quadratic reg part.
// One wave per 16-row tile. W1/W2 fragments resident in VGPRs (loaded once per
// wave). Wave-private LDS for u tile, h tile, C2 tile -> no __syncthreads.

typedef __attribute__((ext_vector_type(8))) __bf16 bf16x8;
typedef __attribute__((ext_vector_type(8))) short short8;
typedef __attribute__((ext_vector_type(4))) float f32x4;

__device__ __forceinline__ unsigned short f2bf(float f) {
    // RNE float -> bf16 bits (inputs finite)
    unsigned int u = __float_as_uint(f);
    unsigned int r = (u + 0x7FFFu + ((u >> 16) & 1u)) >> 16;
    return (unsigned short)r;
}

// --- mfma wrapper: tolerate either V8bf16 or V8i16 builtin signature ---
template <typename A>
__device__ __forceinline__ auto mfma_try(A a, A b, f32x4 c, int)
    -> decltype(__builtin_amdgcn_mfma_f32_16x16x32_bf16(a, b, c, 0, 0, 0)) {
    return __builtin_amdgcn_mfma_f32_16x16x32_bf16(a, b, c, 0, 0, 0);
}
template <typename A>
__device__ __forceinline__ f32x4 mfma_try(A a, A b, f32x4 c, long) {
    return __builtin_amdgcn_mfma_f32_16x16x32_bf16(
        __builtin_bit_cast(short8, a), __builtin_bit_cast(short8, b), c, 0, 0, 0);
}
__device__ __forceinline__ f32x4 mfma_bf16(short8 a, short8 b, f32x4 c) {
    return mfma_try(__builtin_bit_cast(bf16x8, a), __builtin_bit_cast(bf16x8, b), c, 0);
}

__device__ __forceinline__ float tanh_fast(float x) {
    const float e2 = __expf(2.0f * x);
    return 1.0f - __fdividef(2.0f, e2 + 1.0f);
}

__global__ __launch_bounds__(256, 2) void mixmodel_mfma(
    const float* __restrict__ u,      // N*36
    const float* __restrict__ reg1,   // 6
    const float* __restrict__ reg2,   // 4
    const float* __restrict__ W1,     // 18*128
    const float* __restrict__ b1,     // 128
    const float* __restrict__ W2a,    // 128*54
    const float* __restrict__ b2a,    // 54
    const float* __restrict__ W2b,    // 128*72
    const float* __restrict__ b2b,    // 72
    float* __restrict__ out,          // N*36
    int N)
{
    __shared__ __align__(16) float          u_sh[4][16 * 36];   // 2304 B/wave
    __shared__ __align__(16) unsigned short h_sh[4][16 * 136];  // 4352 B/wave (pad 136)
    __shared__ __align__(16) float          c2_sh[4][16 * 132]; // 8448 B/wave (pad 132)

    const int tid = threadIdx.x;
    const int wid = tid >> 6;
    const int l   = tid & 63;
    const int ln  = l & 15;   // A-row / B-col / C-col index
    const int lg  = l >> 4;   // k-group

    float*          u_l  = u_sh[wid];
    unsigned short* h_l  = h_sh[wid];
    float*          c2_l = c2_sh[wid];

    // ---- resident B1 fragments: W1[k][n], k = lg*8+j (0 for k>=18), n = t*16+ln ----
    short8 b1f[8];
#pragma unroll
    for (int t = 0; t < 8; ++t) {
        short8 v;
#pragma unroll
        for (int j = 0; j < 8; ++j) {
            const int k = lg * 8 + j;
            const float w = (k < 18) ? W1[k * 128 + t * 16 + ln] : 0.0f;
            v[j] = (short)f2bf(w);
        }
        b1f[t] = v;
    }

    // ---- resident B2 fragments: W2comb[k][n], k = kk*32+lg*8+j, n = t*16+ln ----
    short8 b2f[4][8];
#pragma unroll
    for (int kk = 0; kk < 4; ++kk) {
#pragma unroll
        for (int t = 0; t < 8; ++t) {
            const int n = t * 16 + ln;
            short8 v;
#pragma unroll
            for (int j = 0; j < 8; ++j) {
                const int k = kk * 32 + lg * 8 + j;
                float w;
                if (n < 54)       w = W2a[k * 54 + n];
                else if (n < 126) w = W2b[k * 72 + (n - 54)];
                else              w = 0.0f;
                v[j] = (short)f2bf(w);
            }
            b2f[kk][t] = v;
        }
    }

    // ---- biases (per-lane column n = t*16+ln) ----
    float bias1[8], bias2[8];
#pragma unroll
    for (int t = 0; t < 8; ++t) {
        const int n = t * 16 + ln;
        bias1[t] = b1[n];
        bias2[t] = (n < 54) ? b2a[n] : (n < 126 ? b2b[n - 54] : 0.0f);
    }

    // ---- regression coefficients (wave-uniform) ----
    const float r10 = reg1[0], r11 = reg1[1], r12 = reg1[2];
    const float r13 = reg1[3], r14 = reg1[4], r15 = reg1[5];
    const float r20 = reg2[0], r21 = reg2[1], r22 = reg2[2], r23 = reg2[3];

    const int ntiles = (N + 15) >> 4;
    const int nwaves = gridDim.x * 4;
    const float4* ug = reinterpret_cast<const float4*>(u);
    const long gmax = (long)N * 9 - 1;  // last valid float4 index in u

    for (int tile = blockIdx.x * 4 + wid; tile < ntiles; tile += nwaves) {
        const int r0 = tile << 4;

        // ---- stage u tile: 16 rows x 36 f32 = 144 float4, coalesced ----
#pragma unroll
        for (int q = 0; q < 3; ++q) {
            const int idx = q * 64 + l;
            if (idx < 144) {
                long g = (long)r0 * 9 + idx;
                g = g < gmax ? g : gmax;  // clamp (partial last tile)
                *reinterpret_cast<float4*>(&u_l[idx * 4]) = ug[g];
            }
        }

        // ---- A1 fragment: u[row][2k], row = ln, k = lg*8+j (0 for k>=18) ----
        short8 a1;
#pragma unroll
        for (int j = 0; j < 8; ++j) {
            const int k = lg * 8 + j;
            const float v = (k < 18) ? u_l[ln * 36 + 2 * k] : 0.0f;
            a1[j] = (short)f2bf(v);
        }

        // ---- GEMM1: 8 MFMA ----
        f32x4 acc1[8];
#pragma unroll
        for (int t = 0; t < 8; ++t) {
            f32x4 c = bias1[t];  // splat
            acc1[t] = mfma_bf16(a1, b1f[t], c);
        }

        // ---- tanh -> h_lds (bf16, padded stride 136) ----
#pragma unroll
        for (int t = 0; t < 8; ++t) {
#pragma unroll
            for (int r = 0; r < 4; ++r) {
                const float h = tanh_fast(acc1[t][r]);
                h_l[(lg * 4 + r) * 136 + t * 16 + ln] = f2bf(h);
            }
        }

        // ---- A2 fragments: h[row=ln][k = kk*32 + lg*8 .. +7] -> ds_read_b128 ----
        short8 a2f[4];
#pragma unroll
        for (int kk = 0; kk < 4; ++kk)
            a2f[kk] = *reinterpret_cast<const short8*>(&h_l[ln * 136 + kk * 32 + lg * 8]);

        // ---- GEMM2: 32 MFMA ----
        f32x4 acc2[8];
#pragma unroll
        for (int t = 0; t < 8; ++t) acc2[t] = (f32x4)bias2[t];
#pragma unroll
        for (int kk = 0; kk < 4; ++kk) {
#pragma unroll
            for (int t = 0; t < 8; ++t)
                acc2[t] = mfma_bf16(a2f[kk], b2f[kk][t], acc2[t]);
        }

        // ---- C2 -> LDS (row = lg*4+r, col = t*16+ln, stride 132) ----
#pragma unroll
        for (int t = 0; t < 8; ++t) {
#pragma unroll
            for (int r = 0; r < 4; ++r)
                c2_l[(lg * 4 + r) * 132 + t * 16 + ln] = acc2[t][r];
        }

        // ---- epilogue: 16 rows x 18 pairs = 288 items over 64 lanes ----
#pragma unroll
        for (int s = 0; s < 5; ++s) {
            const int w = s * 64 + l;
            if (w < 288) {
                const int row = w / 18;
                const int i   = w - row * 18;
                const int rg  = r0 + row;

                int iA  = 2 * i - 1; if (iA  < 0)   iA  += 36;
                int iM2 = 2 * i - 2; if (iM2 < 0)   iM2 += 36;
                int iP2 = 2 * i + 2; if (iP2 >= 36) iP2 -= 36;
                int iC  = 2 * i + 3; if (iC  >= 36) iC  -= 36;

                const float* uu = &u_l[row * 36];
                const float ue  = uu[2 * i];
                const float uo  = uu[2 * i + 1];   // uB
                const float uA  = uu[iA];
                const float um2 = uu[iM2];
                const float up2 = uu[iP2];
                const float uC  = uu[iC];

                const float* c2 = &c2_l[row * 132];
                const float o00 = c2[3 * i], o01 = c2[3 * i + 1], o02 = c2[3 * i + 2];
                const float o10 = c2[54 + 4 * i],     o11 = c2[54 + 4 * i + 1];
                const float o12 = c2[54 + 4 * i + 2], o13 = c2[54 + 4 * i + 3];

                const float oe = o00 + o01 * uA + o02 * uo;
                const float oo = o10 + o11 * uA + o12 * uo + o13 * uC;

                float re = r10;
                re = fmaf(r11, ue,        re);
                re = fmaf(r12, uo,        re);
                re = fmaf(r13, um2 * uA,  re);
                re = fmaf(r14, uA * up2,  re);
                re = fmaf(r15, ue * uo,   re);

                float ro = r20;
                ro = fmaf(r21, uo,        ro);
                ro = fmaf(r22, uA * ue,   ro);
                ro = fmaf(r23, ue * up2,  ro);

                if (rg < N) {
                    const float2 res = make_float2(oe + re, oo + ro);
                    *reinterpret_cast<float2*>(out + (size_t)rg * 36 + 2 * i) = res;
                }
            }
        }
    }
}

extern "C" void kernel_launch(void* const* d_in, const int* in_sizes, int n_in,
                              void* d_out, int out_size, void* d_ws, size_t ws_size,
                              hipStream_t stream) {
    // d_in order: t, u, reg1, reg2, W1, b1, W2a, b2a, W2b, b2b
    const float* u    = (const float*)d_in[1];
    const float* reg1 = (const float*)d_in[2];
    const float* reg2 = (const float*)d_in[3];
    const float* W1   = (const float*)d_in[4];
    const float* b1   = (const float*)d_in[5];
    const float* W2a  = (const float*)d_in[6];
    const float* b2a  = (const float*)d_in[7];
    const float* W2b  = (const float*)d_in[8];
    const float* b2b  = (const float*)d_in[9];
    float* out = (float*)d_out;

    const int N = in_sizes[1] / 36;
    const int ntiles = (N + 15) / 16;
    int grid = (ntiles + 3) / 4;
    if (grid > 512) grid = 512;
    if (grid < 1) grid = 1;
    mixmodel_mfma<<<grid, 256, 0, stream>>>(u, reg1, reg2, W1, b1,
                                            W2a, b2a, W2b, b2b, out, N);
}

// Round 4
// 87.381 us; speedup vs baseline: 4.6685x; 3.1358x over previous
//
#include <hip/hip_runtime.h>
#include <cstddef>

// Block-cooperative MFMA MixModel:
//   GEMM1: u_even[16 x 18(pad32)] @ W1[18 x 128] -> tanh -> h   (N-dim split: 4 waves x 32 cols)
//   GEMM2: h[16 x 128] @ W2comb[128 x 126(pad128)] -> C2        (N-dim split: 4 waves x 32 cols)
// Weights resident in VGPRs (40/thread -> no spill at launch_bounds(256,4)).
// h exchanged via h_sh[16 rows][136 pad] bf16 LDS: scalar b16 writes,
// ds_read_b128 A-fragment reads (round-2 hardware-verified pattern).
// u double-buffered in LDS with register prefetch of the next tile.

typedef __attribute__((ext_vector_type(8))) __bf16 bf16x8;
typedef __attribute__((ext_vector_type(8))) short short8;
typedef __attribute__((ext_vector_type(4))) float f32x4;

__device__ __forceinline__ unsigned short f2bf(float f) {
    unsigned int u = __float_as_uint(f);
    unsigned int r = (u + 0x7FFFu + ((u >> 16) & 1u)) >> 16;
    return (unsigned short)r;
}

// --- mfma wrapper: tolerate either V8bf16 or V8i16 builtin signature ---
template <typename A>
__device__ __forceinline__ auto mfma_try(A a, A b, f32x4 c, int)
    -> decltype(__builtin_amdgcn_mfma_f32_16x16x32_bf16(a, b, c, 0, 0, 0)) {
    return __builtin_amdgcn_mfma_f32_16x16x32_bf16(a, b, c, 0, 0, 0);
}
template <typename A>
__device__ __forceinline__ f32x4 mfma_try(A a, A b, f32x4 c, long) {
    return __builtin_amdgcn_mfma_f32_16x16x32_bf16(
        __builtin_bit_cast(short8, a), __builtin_bit_cast(short8, b), c, 0, 0, 0);
}
__device__ __forceinline__ f32x4 mfma_bf16(short8 a, short8 b, f32x4 c) {
    return mfma_try(__builtin_bit_cast(bf16x8, a), __builtin_bit_cast(bf16x8, b), c, 0);
}

__device__ __forceinline__ float tanh_fast(float x) {
    const float e2 = __expf(2.0f * x);
    return 1.0f - __fdividef(2.0f, e2 + 1.0f);
}

__global__ __launch_bounds__(256, 4) void mixmodel_mfma4(
    const float* __restrict__ u,      // N*36
    const float* __restrict__ reg1,   // 6
    const float* __restrict__ reg2,   // 4
    const float* __restrict__ W1,     // 18*128
    const float* __restrict__ b1,     // 128
    const float* __restrict__ W2a,    // 128*54
    const float* __restrict__ b2a,    // 54
    const float* __restrict__ W2b,    // 128*72
    const float* __restrict__ b2b,    // 72
    float* __restrict__ out,          // N*36
    int N, int ntiles)
{
    __shared__ __align__(16) float          u_sh[2][16 * 38];   // padded stride 38
    __shared__ __align__(16) unsigned short h_sh[16 * 136];     // h [row][k], padded 136
    __shared__ __align__(16) float          c2s[16 * 132];      // C2 [row][n], padded 132

    const int tid = threadIdx.x;
    const int wid = tid >> 6;
    const int l   = tid & 63;
    const int ln  = l & 15;
    const int lg  = l >> 4;
    const int nb  = wid * 32;   // this wave's output-column base (both GEMMs)

    // ---- resident weight fragments: 2 t-tiles x (B1 + 4xB2) = 40 VGPRs ----
    short8 b1f[2];
    short8 b2f[2][4];
    float bias1[2], bias2[2];
#pragma unroll
    for (int t = 0; t < 2; ++t) {
        const int n = nb + t * 16 + ln;
        short8 v;
#pragma unroll
        for (int j = 0; j < 8; ++j) {
            const int k = lg * 8 + j;
            const float w = (k < 18) ? W1[k * 128 + n] : 0.0f;
            v[j] = (short)f2bf(w);
        }
        b1f[t] = v;
        bias1[t] = b1[n];
        bias2[t] = (n < 54) ? b2a[n] : (n < 126 ? b2b[n - 54] : 0.0f);
#pragma unroll
        for (int kk = 0; kk < 4; ++kk) {
            short8 w2;
#pragma unroll
            for (int j = 0; j < 8; ++j) {
                const int k = kk * 32 + lg * 8 + j;
                float w;
                if (n < 54)       w = W2a[k * 54 + n];
                else if (n < 126) w = W2b[k * 72 + (n - 54)];
                else              w = 0.0f;
                w2[j] = (short)f2bf(w);
            }
            b2f[t][kk] = w2;
        }
    }

    // ---- regression coefficients (wave-uniform -> SGPR) ----
    const float r10 = reg1[0], r11 = reg1[1], r12 = reg1[2];
    const float r13 = reg1[3], r14 = reg1[4], r15 = reg1[5];
    const float r20 = reg2[0], r21 = reg2[1], r22 = reg2[2], r23 = reg2[3];

    const float4* ug = reinterpret_cast<const float4*>(u);
    const long fmax4 = (long)N * 9 - 1;
    const int gs = gridDim.x;

    // ---- prefetch first tile into registers ----
    float4 pf;
    if (tid < 144) {
        long g = (long)blockIdx.x * 144 + tid;
        if (g > fmax4) g = fmax4;
        pf = ug[g];
    }

    int b = 0;
    for (int tile = blockIdx.x; tile < ntiles; tile += gs) {
        // ---- write staged regs to LDS; issue next tile's global load ----
        if (tid < 144) {
            const int row = tid / 9, c4 = tid - row * 9;
            float* dst = &u_sh[b][row * 38 + c4 * 4];
            reinterpret_cast<float2*>(dst)[0] = make_float2(pf.x, pf.y);
            reinterpret_cast<float2*>(dst)[1] = make_float2(pf.z, pf.w);
            if (tile + gs < ntiles) {
                long g = (long)(tile + gs) * 144 + tid;
                if (g > fmax4) g = fmax4;
                pf = ug[g];   // in flight across the whole tile body
            }
        }
        __syncthreads();  // bar1: u_sh[b] ready

        // ---- A1 fragment: u[row=ln][2k], k = lg*8+j (<18) ----
        const float* urow = &u_sh[b][ln * 38];
        short8 a1;
#pragma unroll
        for (int j = 0; j < 8; ++j) {
            const int k = lg * 8 + j;
            const float v = (k < 18) ? urow[2 * k] : 0.0f;
            a1[j] = (short)f2bf(v);
        }

        // ---- GEMM1 (2 MFMA) + tanh -> h_sh[row][k] (scalar b16 writes) ----
#pragma unroll
        for (int t = 0; t < 2; ++t) {
            f32x4 c = bias1[t];
            const f32x4 h4 = mfma_bf16(a1, b1f[t], c);
#pragma unroll
            for (int r = 0; r < 4; ++r)
                h_sh[(lg * 4 + r) * 136 + nb + t * 16 + ln] = f2bf(tanh_fast(h4[r]));
        }
        __syncthreads();  // bar2: h ready

        // ---- A2 fragments: h[row=ln][kk*32+lg*8 .. +7] -> ds_read_b128 ----
        short8 a2f[4];
#pragma unroll
        for (int kk = 0; kk < 4; ++kk)
            a2f[kk] = *reinterpret_cast<const short8*>(&h_sh[ln * 136 + kk * 32 + lg * 8]);

        // ---- GEMM2 (8 MFMA) ----
        f32x4 acc2[2];
#pragma unroll
        for (int t = 0; t < 2; ++t) acc2[t] = (f32x4)bias2[t];
#pragma unroll
        for (int kk = 0; kk < 4; ++kk)
#pragma unroll
            for (int t = 0; t < 2; ++t)
                acc2[t] = mfma_bf16(a2f[kk], b2f[t][kk], acc2[t]);

        // ---- C2 -> LDS ----
#pragma unroll
        for (int t = 0; t < 2; ++t)
#pragma unroll
            for (int r = 0; r < 4; ++r)
                c2s[(lg * 4 + r) * 132 + nb + t * 16 + ln] = acc2[t][r];

        __syncthreads();  // bar3: c2 ready

        // ---- epilogue: 288 pair-items over 256 threads ----
        const int r0 = tile << 4;
#pragma unroll
        for (int s = 0; s < 2; ++s) {
            const int w = s * 256 + tid;
            if (w < 288) {
                const int row = w / 18;
                const int i   = w - row * 18;
                const int rg  = r0 + row;

                int iA  = 2 * i - 1; if (iA  < 0)   iA  += 36;
                int iM2 = 2 * i - 2; if (iM2 < 0)   iM2 += 36;
                int iP2 = 2 * i + 2; if (iP2 >= 36) iP2 -= 36;
                int iC  = 2 * i + 3; if (iC  >= 36) iC  -= 36;

                const float* uu = &u_sh[b][row * 38];
                const float ue  = uu[2 * i];
                const float uo  = uu[2 * i + 1];
                const float uA  = uu[iA];
                const float um2 = uu[iM2];
                const float up2 = uu[iP2];
                const float uC  = uu[iC];

                const float* c2r = &c2s[row * 132];
                const float o00 = c2r[3 * i], o01 = c2r[3 * i + 1], o02 = c2r[3 * i + 2];
                const float o10 = c2r[54 + 4 * i],     o11 = c2r[54 + 4 * i + 1];
                const float o12 = c2r[54 + 4 * i + 2], o13 = c2r[54 + 4 * i + 3];

                const float oe = o00 + o01 * uA + o02 * uo;
                const float oo = o10 + o11 * uA + o12 * uo + o13 * uC;

                float re = r10;
                re = fmaf(r11, ue,       re);
                re = fmaf(r12, uo,       re);
                re = fmaf(r13, um2 * uA, re);
                re = fmaf(r14, uA * up2, re);
                re = fmaf(r15, ue * uo,  re);

                float ro = r20;
                ro = fmaf(r21, uo,       ro);
                ro = fmaf(r22, uA * ue,  ro);
                ro = fmaf(r23, ue * up2, ro);

                if (rg < N)
                    *reinterpret_cast<float2*>(out + (size_t)rg * 36 + 2 * i) =
                        make_float2(oe + re, oo + ro);
            }
        }
        b ^= 1;
    }
}

extern "C" void kernel_launch(void* const* d_in, const int* in_sizes, int n_in,
                              void* d_out, int out_size, void* d_ws, size_t ws_size,
                              hipStream_t stream) {
    // d_in order: t, u, reg1, reg2, W1, b1, W2a, b2a, W2b, b2b
    const float* u    = (const float*)d_in[1];
    const float* reg1 = (const float*)d_in[2];
    const float* reg2 = (const float*)d_in[3];
    const float* W1   = (const float*)d_in[4];
    const float* b1   = (const float*)d_in[5];
    const float* W2a  = (const float*)d_in[6];
    const float* b2a  = (const float*)d_in[7];
    const float* W2b  = (const float*)d_in[8];
    const float* b2b  = (const float*)d_in[9];
    float* out = (float*)d_out;

    const int N = in_sizes[1] / 36;
    const int ntiles = (N + 15) / 16;
    int grid = ntiles < 1024 ? ntiles : 1024;
    if (grid < 1) grid = 1;
    mixmodel_mfma4<<<grid, 256, 0, stream>>>(u, reg1, reg2, W1, b1,
                                             W2a, b2a, W2b, b2b, out, N, ntiles);
}

// Round 6
// 85.573 us; speedup vs baseline: 4.7671x; 1.0211x over previous
//
#include <hip/hip_runtime.h>
#include <cstddef>

// Block-cooperative MFMA MixModel, 32 rows/tile (R4-verified core, mechanically doubled):
//   GEMM1: u_even[32 x 18(pad32)] @ W1[18 x 128] -> tanh -> h   (N-dim: 4 waves x 32 cols)
//   GEMM2: h[32 x 128] @ W2comb[128 x 126(pad128)] -> C2        (N-dim: 4 waves x 32 cols)
// Weights resident in VGPRs (40/thread). h exchanged via h_sh[32][136] bf16 LDS:
// scalar b16 writes, ds_read_b128 A-fragment reads (hardware-verified R2/R4 pattern,
// NO swizzle -- isolating the R5 failure to the swizzle/f2bf half of its delta set).
// u double-buffered in LDS with register prefetch of the next tile.

typedef __attribute__((ext_vector_type(8))) __bf16 bf16x8;
typedef __attribute__((ext_vector_type(8))) short short8;
typedef __attribute__((ext_vector_type(4))) float f32x4;

__device__ __forceinline__ unsigned short f2bf(float f) {
    // manual RNE float->bf16 (R4-verified)
    unsigned int u = __float_as_uint(f);
    unsigned int r = (u + 0x7FFFu + ((u >> 16) & 1u)) >> 16;
    return (unsigned short)r;
}

// --- mfma wrapper: tolerate either V8bf16 or V8i16 builtin signature ---
template <typename A>
__device__ __forceinline__ auto mfma_try(A a, A b, f32x4 c, int)
    -> decltype(__builtin_amdgcn_mfma_f32_16x16x32_bf16(a, b, c, 0, 0, 0)) {
    return __builtin_amdgcn_mfma_f32_16x16x32_bf16(a, b, c, 0, 0, 0);
}
template <typename A>
__device__ __forceinline__ f32x4 mfma_try(A a, A b, f32x4 c, long) {
    return __builtin_amdgcn_mfma_f32_16x16x32_bf16(
        __builtin_bit_cast(short8, a), __builtin_bit_cast(short8, b), c, 0, 0, 0);
}
__device__ __forceinline__ f32x4 mfma_bf16(short8 a, short8 b, f32x4 c) {
    return mfma_try(__builtin_bit_cast(bf16x8, a), __builtin_bit_cast(bf16x8, b), c, 0);
}

__device__ __forceinline__ float tanh_fast(float x) {
    const float e2 = __expf(2.0f * x);
    return 1.0f - __fdividef(2.0f, e2 + 1.0f);
}

__global__ __launch_bounds__(256, 4) void mixmodel_mfma6(
    const float* __restrict__ u,      // N*36
    const float* __restrict__ reg1,   // 6
    const float* __restrict__ reg2,   // 4
    const float* __restrict__ W1,     // 18*128
    const float* __restrict__ b1,     // 128
    const float* __restrict__ W2a,    // 128*54
    const float* __restrict__ b2a,    // 54
    const float* __restrict__ W2b,    // 128*72
    const float* __restrict__ b2b,    // 72
    float* __restrict__ out,          // N*36
    int N, int ntiles)
{
    __shared__ __align__(16) float          u_sh[2][32 * 38];   // 9728 B (pad 38)
    __shared__ __align__(16) unsigned short h_sh[32 * 136];     // 8704 B (pad 136, NO swizzle)
    __shared__ __align__(16) float          c2s[32 * 132];      // 16896 B (pad 132)

    const int tid = threadIdx.x;
    const int wid = tid >> 6;
    const int l   = tid & 63;
    const int ln  = l & 15;
    const int lg  = l >> 4;
    const int nb  = wid * 32;   // this wave's output-column base (both GEMMs)

    // ---- resident weight fragments: 2 t-tiles x (B1 + 4xB2) = 40 VGPRs ----
    short8 b1f[2];
    short8 b2f[2][4];
    float bias1[2], bias2[2];
#pragma unroll
    for (int t = 0; t < 2; ++t) {
        const int n = nb + t * 16 + ln;
        short8 v;
#pragma unroll
        for (int j = 0; j < 8; ++j) {
            const int k = lg * 8 + j;
            const float w = (k < 18) ? W1[k * 128 + n] : 0.0f;
            v[j] = (short)f2bf(w);
        }
        b1f[t] = v;
        bias1[t] = b1[n];
        bias2[t] = (n < 54) ? b2a[n] : (n < 126 ? b2b[n - 54] : 0.0f);
#pragma unroll
        for (int kk = 0; kk < 4; ++kk) {
            short8 w2;
#pragma unroll
            for (int j = 0; j < 8; ++j) {
                const int k = kk * 32 + lg * 8 + j;
                float w;
                if (n < 54)       w = W2a[k * 54 + n];
                else if (n < 126) w = W2b[k * 72 + (n - 54)];
                else              w = 0.0f;
                w2[j] = (short)f2bf(w);
            }
            b2f[t][kk] = w2;
        }
    }

    // ---- regression coefficients (wave-uniform -> SGPR) ----
    const float r10 = reg1[0], r11 = reg1[1], r12 = reg1[2];
    const float r13 = reg1[3], r14 = reg1[4], r15 = reg1[5];
    const float r20 = reg2[0], r21 = reg2[1], r22 = reg2[2], r23 = reg2[3];

    const float4* ug = reinterpret_cast<const float4*>(u);
    const long fmax4 = (long)N * 9 - 1;
    const int gs = gridDim.x;

    // ---- staging map: 288 float4/tile; tid does idx0, tid<32 also idx1 ----
    const int idx0 = tid;
    const int row0 = idx0 / 9, c0 = idx0 - row0 * 9;
    const int idx1 = 256 + tid;
    const int row1 = idx1 / 9, c1 = idx1 - row1 * 9;

    // ---- prefetch first tile ----
    float4 pf0, pf1;
    {
        long g0 = (long)blockIdx.x * 288 + idx0; if (g0 > fmax4) g0 = fmax4;
        pf0 = ug[g0];
        if (tid < 32) {
            long g1 = (long)blockIdx.x * 288 + idx1; if (g1 > fmax4) g1 = fmax4;
            pf1 = ug[g1];
        }
    }

    int b = 0;
    for (int tile = blockIdx.x; tile < ntiles; tile += gs) {
        // ---- write staged regs to LDS; issue next tile's global load ----
        {
            float* dst = &u_sh[b][row0 * 38 + c0 * 4];
            reinterpret_cast<float2*>(dst)[0] = make_float2(pf0.x, pf0.y);
            reinterpret_cast<float2*>(dst)[1] = make_float2(pf0.z, pf0.w);
            if (tid < 32) {
                float* dst1 = &u_sh[b][row1 * 38 + c1 * 4];
                reinterpret_cast<float2*>(dst1)[0] = make_float2(pf1.x, pf1.y);
                reinterpret_cast<float2*>(dst1)[1] = make_float2(pf1.z, pf1.w);
            }
            if (tile + gs < ntiles) {
                long g0 = (long)(tile + gs) * 288 + idx0; if (g0 > fmax4) g0 = fmax4;
                pf0 = ug[g0];
                if (tid < 32) {
                    long g1 = (long)(tile + gs) * 288 + idx1; if (g1 > fmax4) g1 = fmax4;
                    pf1 = ug[g1];
                }
            }
        }
        __syncthreads();  // bar1: u_sh[b] ready

        // ---- GEMM1 (2 rb x 2 t MFMA) + tanh -> h_sh (plain b16 writes) ----
#pragma unroll
        for (int rb = 0; rb < 2; ++rb) {
            const float* urow = &u_sh[b][(rb * 16 + ln) * 38];
            short8 a1;
#pragma unroll
            for (int j = 0; j < 8; ++j) {
                const int k = lg * 8 + j;
                const float v = (k < 18) ? urow[2 * k] : 0.0f;
                a1[j] = (short)f2bf(v);
            }
#pragma unroll
            for (int t = 0; t < 2; ++t) {
                f32x4 c = bias1[t];
                const f32x4 h4 = mfma_bf16(a1, b1f[t], c);
#pragma unroll
                for (int r = 0; r < 4; ++r)
                    h_sh[(rb * 16 + lg * 4 + r) * 136 + nb + t * 16 + ln] =
                        f2bf(tanh_fast(h4[r]));
            }
        }
        __syncthreads();  // bar2: h ready

        // ---- GEMM2: A2 via plain ds_read_b128, 16 MFMA ----
        f32x4 acc2[2][2];
#pragma unroll
        for (int rb = 0; rb < 2; ++rb)
#pragma unroll
            for (int t = 0; t < 2; ++t) acc2[rb][t] = (f32x4)bias2[t];

#pragma unroll
        for (int rb = 0; rb < 2; ++rb) {
            const int arow = rb * 16 + ln;
#pragma unroll
            for (int kk = 0; kk < 4; ++kk) {
                const short8 a2 = *reinterpret_cast<const short8*>(
                    &h_sh[arow * 136 + kk * 32 + lg * 8]);
#pragma unroll
                for (int t = 0; t < 2; ++t)
                    acc2[rb][t] = mfma_bf16(a2, b2f[t][kk], acc2[rb][t]);
            }
        }

        // ---- C2 -> LDS ----
#pragma unroll
        for (int rb = 0; rb < 2; ++rb)
#pragma unroll
            for (int t = 0; t < 2; ++t)
#pragma unroll
                for (int r = 0; r < 4; ++r)
                    c2s[(rb * 16 + lg * 4 + r) * 132 + nb + t * 16 + ln] =
                        acc2[rb][t][r];
        __syncthreads();  // bar3: c2 ready

        // ---- epilogue: 576 pair-items over 256 threads (R4 pattern x2) ----
        const int r0 = tile * 32;
#pragma unroll
        for (int s = 0; s < 3; ++s) {
            const int w = s * 256 + tid;
            if (w < 576) {
                const int row = w / 18;
                const int i   = w - row * 18;
                const int rg  = r0 + row;

                int iA  = 2 * i - 1; if (iA  < 0)   iA  += 36;
                int iM2 = 2 * i - 2; if (iM2 < 0)   iM2 += 36;
                int iP2 = 2 * i + 2; if (iP2 >= 36) iP2 -= 36;
                int iC  = 2 * i + 3; if (iC  >= 36) iC  -= 36;

                const float* uu = &u_sh[b][row * 38];
                const float ue  = uu[2 * i];
                const float uo  = uu[2 * i + 1];
                const float uA  = uu[iA];
                const float um2 = uu[iM2];
                const float up2 = uu[iP2];
                const float uC  = uu[iC];

                const float* c2r = &c2s[row * 132];
                const float o00 = c2r[3 * i], o01 = c2r[3 * i + 1], o02 = c2r[3 * i + 2];
                const float o10 = c2r[54 + 4 * i],     o11 = c2r[54 + 4 * i + 1];
                const float o12 = c2r[54 + 4 * i + 2], o13 = c2r[54 + 4 * i + 3];

                const float oe = o00 + o01 * uA + o02 * uo;
                const float oo = o10 + o11 * uA + o12 * uo + o13 * uC;

                float re = r10;
                re = fmaf(r11, ue,       re);
                re = fmaf(r12, uo,       re);
                re = fmaf(r13, um2 * uA, re);
                re = fmaf(r14, uA * up2, re);
                re = fmaf(r15, ue * uo,  re);

                float ro = r20;
                ro = fmaf(r21, uo,       ro);
                ro = fmaf(r22, uA * ue,  ro);
                ro = fmaf(r23, ue * up2, ro);

                if (rg < N)
                    *reinterpret_cast<float2*>(out + (size_t)rg * 36 + 2 * i) =
                        make_float2(oe + re, oo + ro);
            }
        }
        b ^= 1;
    }
}

extern "C" void kernel_launch(void* const* d_in, const int* in_sizes, int n_in,
                              void* d_out, int out_size, void* d_ws, size_t ws_size,
                              hipStream_t stream) {
    // d_in order: t, u, reg1, reg2, W1, b1, W2a, b2a, W2b, b2b
    const float* u    = (const float*)d_in[1];
    const float* reg1 = (const float*)d_in[2];
    const float* reg2 = (const float*)d_in[3];
    const float* W1   = (const float*)d_in[4];
    const float* b1   = (const float*)d_in[5];
    const float* W2a  = (const float*)d_in[6];
    const float* b2a  = (const float*)d_in[7];
    const float* W2b  = (const float*)d_in[8];
    const float* b2b  = (const float*)d_in[9];
    float* out = (float*)d_out;

    const int N = in_sizes[1] / 36;
    const int ntiles = (N + 31) / 32;
    int grid = ntiles < 1024 ? ntiles : 1024;
    if (grid < 1) grid = 1;
    mixmodel_mfma6<<<grid, 256, 0, stream>>>(u, reg1, reg2, W1, b1,
                                             W2a, b2a, W2b, b2b, out, N, ntiles);
}

// Round 8
// 80.733 us; speedup vs baseline: 5.0529x; 1.0600x over previous
//
#include <hip/hip_runtime.h>
#include <cstddef>

// Block-cooperative MFMA MixModel, 32 rows/tile, LDS-op-minimized (R7 + stride fix):
//   GEMM1: u_even[32 x 18(pad32)] @ W1 -> tanh -> h   (N-dim: 4 waves x 32 cols)
//   GEMM2: h[32 x 128] @ W2comb[128 x 126(pad128)] -> C2
//   - u_bf[32][32]: pre-converted bf16 evens (pads zeroed once) -> a1 = 1 ds_read_b128
//   - u_ext[32][40]: halo'd f32 rows -> epilogue u reads = 3 ds_read_b64, no wraps
//   - c2s[32][144] quad-interleaved [8i+slot] -> epilogue c2 reads = 2 ds_read_b128
//     (R7 BUG: stride was 132 but max in-row index is 143 -> cross-row aliasing + OOB.
//      Fixed: stride/size 144. Rows stay 16B-aligned: 144*4 = 576 B.)
// h exchange keeps the R2/R4/R6 hardware-verified pattern (stride 136, no swizzle).

typedef __attribute__((ext_vector_type(8))) __bf16 bf16x8;
typedef __attribute__((ext_vector_type(8))) short short8;
typedef __attribute__((ext_vector_type(4))) float f32x4;

__device__ __forceinline__ unsigned short f2bf(float f) {
    // manual RNE float->bf16 (R4/R6-verified)
    unsigned int u = __float_as_uint(f);
    unsigned int r = (u + 0x7FFFu + ((u >> 16) & 1u)) >> 16;
    return (unsigned short)r;
}

// --- mfma wrapper: tolerate either V8bf16 or V8i16 builtin signature ---
template <typename A>
__device__ __forceinline__ auto mfma_try(A a, A b, f32x4 c, int)
    -> decltype(__builtin_amdgcn_mfma_f32_16x16x32_bf16(a, b, c, 0, 0, 0)) {
    return __builtin_amdgcn_mfma_f32_16x16x32_bf16(a, b, c, 0, 0, 0);
}
template <typename A>
__device__ __forceinline__ f32x4 mfma_try(A a, A b, f32x4 c, long) {
    return __builtin_amdgcn_mfma_f32_16x16x32_bf16(
        __builtin_bit_cast(short8, a), __builtin_bit_cast(short8, b), c, 0, 0, 0);
}
__device__ __forceinline__ f32x4 mfma_bf16(short8 a, short8 b, f32x4 c) {
    return mfma_try(__builtin_bit_cast(bf16x8, a), __builtin_bit_cast(bf16x8, b), c, 0);
}

__device__ __forceinline__ float tanh_fast(float x) {
    const float e2 = __expf(2.0f * x);
    return 1.0f - __fdividef(2.0f, e2 + 1.0f);
}

__global__ __launch_bounds__(256, 4) void mixmodel_mfma8(
    const float* __restrict__ u,      // N*36
    const float* __restrict__ reg1,   // 6
    const float* __restrict__ reg2,   // 4
    const float* __restrict__ W1,     // 18*128
    const float* __restrict__ b1,     // 128
    const float* __restrict__ W2a,    // 128*54
    const float* __restrict__ b2a,    // 54
    const float* __restrict__ W2b,    // 128*72
    const float* __restrict__ b2b,    // 72
    float* __restrict__ out,          // N*36
    int N, int ntiles)
{
    __shared__ __align__(16) float          u_ext[32 * 40];   // 5120 B: [u34,u35 | u0..u35 | u0,u1]
    __shared__ __align__(16) unsigned short h_sh[32 * 136];   // 8704 B (R6-verified layout)
    __shared__ __align__(16) unsigned short u_bf[32 * 32];    // 2048 B: bf16 evens, pads zero
    __shared__ __align__(16) float          c2s[32 * 144];    // 18432 B: [row][8i+slot], stride 144
    // total = 34304 B -> 4 blocks/CU

    const int tid = threadIdx.x;
    const int wid = tid >> 6;
    const int l   = tid & 63;
    const int ln  = l & 15;
    const int lg  = l >> 4;
    const int nb  = wid * 32;

    // ---- zero u_bf (pads persist; real slots rewritten each tile) ----
    reinterpret_cast<unsigned int*>(u_bf)[tid]       = 0u;
    reinterpret_cast<unsigned int*>(u_bf)[tid + 256] = 0u;
    __syncthreads();  // close init/staging cross-wave race

    // ---- resident weight fragments: 2 t-tiles x (B1 + 4xB2) = 40 VGPRs ----
    short8 b1f[2];
    short8 b2f[2][4];
    float bias1[2], bias2[2];
    int c2idx[2];   // quad-interleaved in-row index for this lane's C2 writes (max 143)
#pragma unroll
    for (int t = 0; t < 2; ++t) {
        const int n = nb + t * 16 + ln;
        short8 v;
#pragma unroll
        for (int j = 0; j < 8; ++j) {
            const int k = lg * 8 + j;
            const float w = (k < 18) ? W1[k * 128 + n] : 0.0f;
            v[j] = (short)f2bf(w);
        }
        b1f[t] = v;
        bias1[t] = b1[n];
        bias2[t] = (n < 54) ? b2a[n] : (n < 126 ? b2b[n - 54] : 0.0f);
        if (n < 54)       c2idx[t] = (n / 3) * 8 + (n % 3);
        else if (n < 126) { const int m = n - 54; c2idx[t] = (m >> 2) * 8 + 4 + (m & 3); }
        else              c2idx[t] = 3;  // dump slot (i=0 pad), never read
#pragma unroll
        for (int kk = 0; kk < 4; ++kk) {
            short8 w2;
#pragma unroll
            for (int j = 0; j < 8; ++j) {
                const int k = kk * 32 + lg * 8 + j;
                float w;
                if (n < 54)       w = W2a[k * 54 + n];
                else if (n < 126) w = W2b[k * 72 + (n - 54)];
                else              w = 0.0f;
                w2[j] = (short)f2bf(w);
            }
            b2f[t][kk] = w2;
        }
    }

    // ---- regression coefficients (wave-uniform -> SGPR) ----
    const float r10 = reg1[0], r11 = reg1[1], r12 = reg1[2];
    const float r13 = reg1[3], r14 = reg1[4], r15 = reg1[5];
    const float r20 = reg2[0], r21 = reg2[1], r22 = reg2[2], r23 = reg2[3];

    const float4* ug = reinterpret_cast<const float4*>(u);
    const long fmax4 = (long)N * 9 - 1;
    const int gs = gridDim.x;

    // ---- staging maps ----
    const int row0 = tid / 9,          c0 = tid - row0 * 9;          // main float4
    const int row1 = (256 + tid) / 9,  c1 = (256 + tid) - row1 * 9;  // tid<32 extra
    const int hrow = (tid - 192) >> 1, hside = tid & 1;              // tid>=192: halos

    // ---- prefetch first tile ----
    float4 pf0, pf1; float2 pfh;
    {
        const int r0 = blockIdx.x * 32;
        long g0 = (long)r0 * 9 + tid; if (g0 > fmax4) g0 = fmax4;
        pf0 = ug[g0];
        if (tid < 32) {
            long g1 = (long)r0 * 9 + 256 + tid; if (g1 > fmax4) g1 = fmax4;
            pf1 = ug[g1];
        }
        if (tid >= 192) {
            int rr = r0 + hrow; if (rr > N - 1) rr = N - 1;
            pfh = *reinterpret_cast<const float2*>(u + (size_t)rr * 36 + (hside ? 0 : 34));
        }
    }

    for (int tile = blockIdx.x; tile < ntiles; tile += gs) {
        // ---- stage: u_ext (f32+halo), u_bf (bf16 evens); prefetch next ----
        {
            float* dst = &u_ext[row0 * 40 + 2 + c0 * 4];
            reinterpret_cast<float2*>(dst)[0] = make_float2(pf0.x, pf0.y);
            reinterpret_cast<float2*>(dst)[1] = make_float2(pf0.z, pf0.w);
            // evens: col 4c0 -> ke 2c0, col 4c0+2 -> ke 2c0+1
            reinterpret_cast<unsigned int*>(u_bf)[row0 * 16 + c0] =
                (unsigned int)f2bf(pf0.x) | ((unsigned int)f2bf(pf0.z) << 16);
            if (tid < 32) {
                float* dst1 = &u_ext[row1 * 40 + 2 + c1 * 4];
                reinterpret_cast<float2*>(dst1)[0] = make_float2(pf1.x, pf1.y);
                reinterpret_cast<float2*>(dst1)[1] = make_float2(pf1.z, pf1.w);
                reinterpret_cast<unsigned int*>(u_bf)[row1 * 16 + c1] =
                    (unsigned int)f2bf(pf1.x) | ((unsigned int)f2bf(pf1.z) << 16);
            }
            if (tid >= 192)
                *reinterpret_cast<float2*>(&u_ext[hrow * 40 + (hside ? 38 : 0)]) = pfh;

            if (tile + gs < ntiles) {
                const int r0n = (tile + gs) * 32;
                long g0 = (long)r0n * 9 + tid; if (g0 > fmax4) g0 = fmax4;
                pf0 = ug[g0];
                if (tid < 32) {
                    long g1 = (long)r0n * 9 + 256 + tid; if (g1 > fmax4) g1 = fmax4;
                    pf1 = ug[g1];
                }
                if (tid >= 192) {
                    int rr = r0n + hrow; if (rr > N - 1) rr = N - 1;
                    pfh = *reinterpret_cast<const float2*>(u + (size_t)rr * 36 + (hside ? 0 : 34));
                }
            }
        }
        __syncthreads();  // bar1: u_ext/u_bf ready

        // ---- GEMM1: a1 = 1 ds_read_b128 from u_bf; + tanh -> h_sh ----
#pragma unroll
        for (int rb = 0; rb < 2; ++rb) {
            const short8 a1 = *reinterpret_cast<const short8*>(
                &u_bf[(rb * 16 + ln) * 32 + lg * 8]);
#pragma unroll
            for (int t = 0; t < 2; ++t) {
                f32x4 c = bias1[t];
                const f32x4 h4 = mfma_bf16(a1, b1f[t], c);
#pragma unroll
                for (int r = 0; r < 4; ++r)
                    h_sh[(rb * 16 + lg * 4 + r) * 136 + nb + t * 16 + ln] =
                        f2bf(tanh_fast(h4[r]));
            }
        }
        __syncthreads();  // bar2: h ready

        // ---- GEMM2: A2 via plain ds_read_b128, 16 MFMA ----
        f32x4 acc2[2][2];
#pragma unroll
        for (int rb = 0; rb < 2; ++rb)
#pragma unroll
            for (int t = 0; t < 2; ++t) acc2[rb][t] = (f32x4)bias2[t];

#pragma unroll
        for (int rb = 0; rb < 2; ++rb) {
            const int arow = rb * 16 + ln;
#pragma unroll
            for (int kk = 0; kk < 4; ++kk) {
                const short8 a2 = *reinterpret_cast<const short8*>(
                    &h_sh[arow * 136 + kk * 32 + lg * 8]);
#pragma unroll
                for (int t = 0; t < 2; ++t)
                    acc2[rb][t] = mfma_bf16(a2, b2f[t][kk], acc2[rb][t]);
            }
        }

        // ---- C2 -> LDS, quad-interleaved [row][8i+slot], stride 144 ----
#pragma unroll
        for (int rb = 0; rb < 2; ++rb)
#pragma unroll
            for (int t = 0; t < 2; ++t)
#pragma unroll
                for (int r = 0; r < 4; ++r)
                    c2s[(rb * 16 + lg * 4 + r) * 144 + c2idx[t]] = acc2[rb][t][r];
        __syncthreads();  // bar3: c2 ready

        // ---- epilogue: 576 pair-items, 5 vector LDS reads each ----
        const int r0 = tile * 32;
#pragma unroll
        for (int s = 0; s < 3; ++s) {
            const int w = s * 256 + tid;
            if (w < 576) {
                const int row = w / 18;
                const int i   = w - row * 18;
                const int rg  = r0 + row;

                const float2 v0 = *reinterpret_cast<const float2*>(&u_ext[row * 40 + 2 * i]);      // u[2i-2], u[2i-1]
                const float2 v1 = *reinterpret_cast<const float2*>(&u_ext[row * 40 + 2 * i + 2]);  // u[2i],   u[2i+1]
                const float2 v2 = *reinterpret_cast<const float2*>(&u_ext[row * 40 + 2 * i + 4]);  // u[2i+2], u[2i+3]
                const f32x4  q0 = *reinterpret_cast<const f32x4*>(&c2s[row * 144 + 8 * i]);        // o00,o01,o02,(pad)
                const f32x4  q1 = *reinterpret_cast<const f32x4*>(&c2s[row * 144 + 8 * i + 4]);    // o10..o13

                const float um2 = v0.x, uA = v0.y;
                const float ue  = v1.x, uo = v1.y;
                const float up2 = v2.x, uC = v2.y;

                const float oe = q0[0] + q0[1] * uA + q0[2] * uo;
                const float oo = q1[0] + q1[1] * uA + q1[2] * uo + q1[3] * uC;

                float re = r10;
                re = fmaf(r11, ue,       re);
                re = fmaf(r12, uo,       re);
                re = fmaf(r13, um2 * uA, re);
                re = fmaf(r14, uA * up2, re);
                re = fmaf(r15, ue * uo,  re);

                float ro = r20;
                ro = fmaf(r21, uo,       ro);
                ro = fmaf(r22, uA * ue,  ro);
                ro = fmaf(r23, ue * up2, ro);

                if (rg < N)
                    *reinterpret_cast<float2*>(out + (size_t)rg * 36 + 2 * i) =
                        make_float2(oe + re, oo + ro);
            }
        }
        __syncthreads();  // bar4: u_ext/u_bf/c2s free for next tile's staging
    }
}

extern "C" void kernel_launch(void* const* d_in, const int* in_sizes, int n_in,
                              void* d_out, int out_size, void* d_ws, size_t ws_size,
                              hipStream_t stream) {
    // d_in order: t, u, reg1, reg2, W1, b1, W2a, b2a, W2b, b2b
    const float* u    = (const float*)d_in[1];
    const float* reg1 = (const float*)d_in[2];
    const float* reg2 = (const float*)d_in[3];
    const float* W1   = (const float*)d_in[4];
    const float* b1   = (const float*)d_in[5];
    const float* W2a  = (const float*)d_in[6];
    const float* b2a  = (const float*)d_in[7];
    const float* W2b  = (const float*)d_in[8];
    const float* b2b  = (const float*)d_in[9];
    float* out = (float*)d_out;

    const int N = in_sizes[1] / 36;
    const int ntiles = (N + 31) / 32;
    int grid = ntiles < 1024 ? ntiles : 1024;
    if (grid < 1) grid = 1;
    mixmodel_mfma8<<<grid, 256, 0, stream>>>(u, reg1, reg2, W1, b1,
                                             W2a, b2a, W2b, b2b, out, N, ntiles);
}